// Round 2
// baseline (532.798 us; speedup 1.0000x reference)
//
#include <hip/hip_runtime.h>

#define NB 16
#define DMODEL 4096
#define NH 32
#define NKV 8
#define HD 128
#define SEQ 4096
#define PASTN 4095
#define EQKV 6144           // 4096 q + 1024 k + 1024 v rows
#define NCHUNK 8
#define CHUNKS 512
#define STILE 32
#define SCALE 0.08838834764831845f  // 1/sqrt(128)

// ---------------- Kernel 1: fused QKV projection (M=16, N=6144, K=4096) ----
// One output row per wave; grid 1536 blocks -> 6 blocks/CU, 24 waves/CU.
__global__ __launch_bounds__(256) void qkv_proj(
    const float* __restrict__ hs, const float* __restrict__ Wq,
    const float* __restrict__ Wk, const float* __restrict__ Wv,
    float* __restrict__ raw /* [B][6144] */) {
  __shared__ float red[4][32][17];
  const int wid = threadIdx.x >> 6, lane = threadIdx.x & 63;
  const int e = blockIdx.x * 4 + wid;

  const float* wrow = (e < 4096) ? (Wq + (size_t)e * DMODEL)
                    : (e < 5120) ? (Wk + (size_t)(e - 4096) * DMODEL)
                                 : (Wv + (size_t)(e - 5120) * DMODEL);

  float acc[16];
#pragma unroll
  for (int b = 0; b < 16; ++b) acc[b] = 0.f;

  for (int k0 = 0; k0 < DMODEL; k0 += 256) {
    const int k = k0 + lane * 4;
    float4 w4 = *(const float4*)(wrow + k);
#pragma unroll
    for (int b = 0; b < 16; ++b) {
      float4 h4 = *(const float4*)(hs + (size_t)b * DMODEL + k);
      acc[b] += w4.x * h4.x + w4.y * h4.y + w4.z * h4.z + w4.w * h4.w;
    }
  }

#pragma unroll
  for (int b = 0; b < 16; ++b) acc[b] += __shfl_xor(acc[b], 32);

  if (lane < 32) {
#pragma unroll
    for (int b = 0; b < 16; ++b) red[wid][lane][b] = acc[b];
  }
  __syncthreads();

  if (lane < 16) {
    float s = 0.f;
#pragma unroll
    for (int l = 0; l < 32; ++l) s += red[wid][l][lane];
    raw[(size_t)lane * EQKV + e] = s;
  }
}

// ---------------- Kernel 2: RoPE + scatter new row into caches ------------
__device__ __forceinline__ float rope_val(const float* src, int d, float pos) {
  int i = d & 63;
  float inv_freq = powf(10000.f, -(float)(2 * i) * (1.f / 128.f));
  float ang = pos * inv_freq;
  float s, c;
  sincosf(ang, &s, &c);
  float x = src[d];
  float rot = (d < 64) ? -src[d + 64] : src[d - 64];
  return x * c + rot * s;
}

__global__ void rope_scatter(const float* __restrict__ raw,
                             const void* __restrict__ pos_ids,
                             float* __restrict__ qout,
                             float* __restrict__ kc, float* __restrict__ vc) {
  const int b = blockIdx.y, j = blockIdx.x, d = threadIdx.x;  // 128 threads
  const int* pi = (const int*)pos_ids;
  long long pos = (pi[1] == 0 && pi[0] != 0) ? ((const long long*)pos_ids)[b]
                                             : (long long)pi[b];
  const float fpos = (float)pos;
  if (j < 32) {
    const float* src = raw + (size_t)b * EQKV + j * HD;
    qout[(size_t)b * (NH * HD) + j * HD + d] = rope_val(src, d, fpos);
  } else if (j < 40) {
    int kvh = j - 32;
    const float* src = raw + (size_t)b * EQKV + 4096 + kvh * HD;
    kc[(((size_t)b * NKV + kvh) * SEQ + PASTN) * HD + d] = rope_val(src, d, fpos);
  } else {
    int kvh = j - 40;
    vc[(((size_t)b * NKV + kvh) * SEQ + PASTN) * HD + d] =
        raw[(size_t)b * EQKV + 5120 + kvh * HD + d];
  }
}

// ---------------- Kernel 3: fused cache-copy + flash-decode attention -----
// grid (chunk=8, kv=8, b=16); 256 threads = 4 waves = 4 heads per kv group.
// T14 async-STAGE: prefetch tile t+1 into regs while computing tile t.
__global__ __launch_bounds__(256, 4) void attn_decode(
    const float* __restrict__ pastK, const float* __restrict__ pastV,
    const float* __restrict__ qv, const float* __restrict__ mask,
    float* __restrict__ kc, float* __restrict__ vc,
    float* __restrict__ part /* [B][32][8][130] */) {
  __shared__ float kt[STILE][132];
  __shared__ float vt[STILE][132];
  __shared__ float qs[4][HD];
  __shared__ float ps[4][STILE];

  const int chunk = blockIdx.x, kv = blockIdx.y, b = blockIdx.z;
  const int tid = threadIdx.x, wid = tid >> 6, lane = tid & 63;
  const int half = lane >> 5, sl = lane & 31;
  const int srow0 = tid >> 5;   // rows: i*8 + srow0
  const int c4 = tid & 31;      // float4 column

  for (int i = tid; i < 4 * HD; i += 256)
    qs[i >> 7][i & 127] = qv[(size_t)b * (NH * HD) + (kv * 4 + (i >> 7)) * HD + (i & 127)];

  const size_t cbase = ((size_t)b * NKV + kv) * SEQ;
  const size_t pbase = ((size_t)b * NKV + kv) * PASTN;

  float m = -1e30f, l = 0.f;
  float2 cacc = {0.f, 0.f};
  float4 kreg[4], vreg[4];

  // prologue: load tile 0 into registers
  {
    const int s0 = chunk * CHUNKS;
#pragma unroll
    for (int i = 0; i < 4; ++i) {
      int s = s0 + i * 8 + srow0;
      if (s < PASTN) {
        size_t poff = (pbase + s) * HD + c4 * 4;
        kreg[i] = *(const float4*)(pastK + poff);
        vreg[i] = *(const float4*)(pastV + poff);
      } else {
        size_t coff = (cbase + s) * HD + c4 * 4;
        kreg[i] = *(const float4*)(kc + coff);
        vreg[i] = *(const float4*)(vc + coff);
      }
    }
  }
  __syncthreads();  // qs ready

  for (int t = 0; t < CHUNKS / STILE; ++t) {
    const int s0 = chunk * CHUNKS + t * STILE;

    // stage-write: regs -> LDS + cache write-through
#pragma unroll
    for (int i = 0; i < 4; ++i) {
      int row = i * 8 + srow0;
      int s = s0 + row;
      *(float4*)(&kt[row][c4 * 4]) = kreg[i];
      *(float4*)(&vt[row][c4 * 4]) = vreg[i];
      if (s < PASTN) {
        size_t coff = (cbase + s) * HD + c4 * 4;
        *(float4*)(kc + coff) = kreg[i];
        *(float4*)(vc + coff) = vreg[i];
      }
    }
    __syncthreads();

    // prefetch tile t+1 into regs (overlaps with compute below)
    if (t + 1 < CHUNKS / STILE) {
      const int s1 = s0 + STILE;
#pragma unroll
      for (int i = 0; i < 4; ++i) {
        int s = s1 + i * 8 + srow0;
        if (s < PASTN) {
          size_t poff = (pbase + s) * HD + c4 * 4;
          kreg[i] = *(const float4*)(pastK + poff);
          vreg[i] = *(const float4*)(pastV + poff);
        } else {
          size_t coff = (cbase + s) * HD + c4 * 4;
          kreg[i] = *(const float4*)(kc + coff);
          vreg[i] = *(const float4*)(vc + coff);
        }
      }
    }

    // scores: lane-half computes 64 dims via float4 LDS reads
    float dot = 0.f;
    const float4* q4 = (const float4*)(&qs[wid][half * 64]);
    const float4* k4 = (const float4*)(&kt[sl][half * 64]);
#pragma unroll
    for (int d = 0; d < 16; ++d) {
      float4 a = q4[d], c = k4[d];
      dot += a.x * c.x + a.y * c.y + a.z * c.z + a.w * c.w;
    }
    dot += __shfl_xor(dot, 32);

    const int s = s0 + sl;
    float sc = dot * SCALE + mask[(size_t)b * SEQ + s];

    float tm = sc;
#pragma unroll
    for (int o = 16; o >= 1; o >>= 1) tm = fmaxf(tm, __shfl_xor(tm, o));
    float mn = fmaxf(m, tm);
    float p = __expf(sc - mn);
    float alpha = __expf(m - mn);
    float psum = p;
#pragma unroll
    for (int o = 16; o >= 1; o >>= 1) psum += __shfl_xor(psum, o);
    l = l * alpha + psum;
    cacc.x *= alpha;
    cacc.y *= alpha;
    m = mn;

    if (half == 0) ps[wid][sl] = p;
    // wave-local LDS RAW (wave-synchronous, in-order ds pipe)
    for (int sp = 0; sp < STILE; ++sp) {
      float pv = ps[wid][sp];
      float2 v2 = *(const float2*)(&vt[sp][lane * 2]);
      cacc.x += pv * v2.x;
      cacc.y += pv * v2.y;
    }
    __syncthreads();
  }

  const int h = kv * 4 + wid;
  float* pp = part + (((size_t)b * NH + h) * NCHUNK + chunk) * 130;
  if (lane == 0) { pp[0] = m; pp[1] = l; }
  *(float2*)(pp + 2 + 2 * lane) = cacc;   // cols 2*lane, 2*lane+1
}

// ---------------- Kernel 4: combine chunk partials ------------------------
__global__ void combine(const float* __restrict__ part, float* __restrict__ ctx) {
  const int bh = blockIdx.x;        // 0..511
  const int lane = threadIdx.x;     // 64
  const float* pp = part + (size_t)bh * NCHUNK * 130;
  float mstar = -1e30f;
#pragma unroll
  for (int c = 0; c < NCHUNK; ++c) mstar = fmaxf(mstar, pp[c * 130]);
  float den = 0.f;
  float2 n = {0.f, 0.f};
#pragma unroll
  for (int c = 0; c < NCHUNK; ++c) {
    float w = __expf(pp[c * 130] - mstar);
    den += w * pp[c * 130 + 1];
    float2 pv = *(const float2*)(pp + c * 130 + 2 + 2 * lane);
    n.x += w * pv.x;
    n.y += w * pv.y;
  }
  float inv = 1.0f / den;
  ctx[(size_t)bh * HD + 2 * lane] = n.x * inv;
  ctx[(size_t)bh * HD + 2 * lane + 1] = n.y * inv;
}

// ---------------- Kernel 5: output projection (M=16, N=4096, K=4096) ------
// One output row per wave; grid 1024 blocks.
__global__ __launch_bounds__(256) void out_proj(
    const float* __restrict__ ctx, const float* __restrict__ Wo,
    float* __restrict__ out) {
  __shared__ float red[4][32][17];
  const int wid = threadIdx.x >> 6, lane = threadIdx.x & 63;
  const int e = blockIdx.x * 4 + wid;
  const float* wrow = Wo + (size_t)e * DMODEL;

  float acc[16];
#pragma unroll
  for (int b = 0; b < 16; ++b) acc[b] = 0.f;

  for (int k0 = 0; k0 < DMODEL; k0 += 256) {
    const int k = k0 + lane * 4;
    float4 w4 = *(const float4*)(wrow + k);
#pragma unroll
    for (int b = 0; b < 16; ++b) {
      float4 h4 = *(const float4*)(ctx + (size_t)b * DMODEL + k);
      acc[b] += w4.x * h4.x + w4.y * h4.y + w4.z * h4.z + w4.w * h4.w;
    }
  }

#pragma unroll
  for (int b = 0; b < 16; ++b) acc[b] += __shfl_xor(acc[b], 32);

  if (lane < 32) {
#pragma unroll
    for (int b = 0; b < 16; ++b) red[wid][lane][b] = acc[b];
  }
  __syncthreads();

  if (lane < 16) {
    float s = 0.f;
#pragma unroll
    for (int l = 0; l < 32; ++l) s += red[wid][l][lane];
    out[(size_t)lane * DMODEL + e] = s;
  }
}

// ---------------------------------------------------------------------------
extern "C" void kernel_launch(void* const* d_in, const int* in_sizes, int n_in,
                              void* d_out, int out_size, void* d_ws, size_t ws_size,
                              hipStream_t stream) {
  const float* hs    = (const float*)d_in[0];
  const float* mask  = (const float*)d_in[1];
  const void*  pos   = d_in[2];
  const float* pastK = (const float*)d_in[3];
  const float* pastV = (const float*)d_in[4];
  const float* Wq    = (const float*)d_in[5];
  const float* Wk    = (const float*)d_in[6];
  const float* Wv    = (const float*)d_in[7];
  const float* Wo    = (const float*)d_in[8];

  float* out  = (float*)d_out;
  float* attn = out;                                        // 16*4096
  float* kc   = out + (size_t)NB * DMODEL;                  // 16*8*4096*128
  float* vc   = kc + (size_t)NB * NKV * SEQ * HD;

  float* ws      = (float*)d_ws;
  float* ws_q    = ws;                                      // 65536
  float* ws_raw  = ws_q + (size_t)NB * NH * HD;             // 98304
  float* ws_part = ws_raw + (size_t)NB * EQKV;              // 16*32*8*130
  float* ws_ctx  = ws_part + (size_t)NB * NH * NCHUNK * 130;// 65536

  qkv_proj<<<EQKV / 4, 256, 0, stream>>>(hs, Wq, Wk, Wv, ws_raw);
  rope_scatter<<<dim3(48, NB), 128, 0, stream>>>(ws_raw, pos, ws_q, kc, vc);
  attn_decode<<<dim3(NCHUNK, NKV, NB), 256, 0, stream>>>(pastK, pastV, ws_q, mask,
                                                         kc, vc, ws_part);
  combine<<<NB * NH, 64, 0, stream>>>(ws_part, ws_ctx);
  out_proj<<<DMODEL / 4, 256, 0, stream>>>(ws_ctx, Wo, attn);
}

// Round 3
// 353.198 us; speedup vs baseline: 1.5085x; 1.5085x over previous
//
#include <hip/hip_runtime.h>

#define NB 16
#define DMODEL 4096
#define NH 32
#define NKV 8
#define HD 128
#define SEQ 4096
#define PASTN 4095
#define EQKV 6144           // 4096 q + 1024 k + 1024 v rows
#define NCHUNK 8
#define CHUNKS 512
#define PSTRIDE 136         // partials stride (16B aligned)
#define SCALE 0.08838834764831845f  // 1/sqrt(128)

typedef float v4f __attribute__((ext_vector_type(4)));

// ---------------- Kernel 1: fused QKV projection (M=16, N=6144, K=4096) ----
// 4 waves/block, 4 rows/wave; hs chunk staged in LDS (kills L2 re-reads).
__global__ __launch_bounds__(256) void qkv_proj(
    const float* __restrict__ hs, const float* __restrict__ Wq,
    const float* __restrict__ Wk, const float* __restrict__ Wv,
    float* __restrict__ raw /* [B][6144] */) {
  __shared__ __align__(16) float smem[4 * 32 * 65];  // 33.3 KB; reused: ld then red
  const int tid = threadIdx.x, wid = tid >> 6, lane = tid & 63;
  const int e0 = blockIdx.x * 16 + wid * 4;

  const float* wrow[4];
#pragma unroll
  for (int r = 0; r < 4; ++r) {
    int e = e0 + r;
    wrow[r] = (e < 4096) ? (Wq + (size_t)e * DMODEL)
            : (e < 5120) ? (Wk + (size_t)(e - 4096) * DMODEL)
                         : (Wv + (size_t)(e - 5120) * DMODEL);
  }

  float acc[4][16];
#pragma unroll
  for (int r = 0; r < 4; ++r)
#pragma unroll
    for (int b = 0; b < 16; ++b) acc[r][b] = 0.f;

  float* ld = smem;  // [16][256]
  for (int k0 = 0; k0 < DMODEL; k0 += 256) {
    __syncthreads();
#pragma unroll
    for (int i = 0; i < 4; ++i) {
      int flat = i * 1024 + tid * 4;          // 0..4095
      int b = flat >> 8, c = flat & 255;
      *(v4f*)(&ld[b * 256 + c]) = *(const v4f*)(hs + (size_t)b * DMODEL + k0 + c);
    }
    __syncthreads();
    v4f w4[4];
#pragma unroll
    for (int r = 0; r < 4; ++r) w4[r] = *(const v4f*)(wrow[r] + k0 + lane * 4);
#pragma unroll
    for (int b = 0; b < 16; ++b) {
      v4f h4 = *(const v4f*)(&ld[b * 256 + lane * 4]);
#pragma unroll
      for (int r = 0; r < 4; ++r) {
        v4f t = w4[r] * h4;
        acc[r][b] += t[0] + t[1] + t[2] + t[3];
      }
    }
  }

#pragma unroll
  for (int r = 0; r < 4; ++r)
#pragma unroll
    for (int b = 0; b < 16; ++b) acc[r][b] += __shfl_xor(acc[r][b], 32);

  __syncthreads();  // smem reuse as red[4][32][65]
  if (lane < 32) {
#pragma unroll
    for (int r = 0; r < 4; ++r)
#pragma unroll
      for (int b = 0; b < 16; ++b)
        smem[(wid * 32 + lane) * 65 + r * 16 + b] = acc[r][b];
  }
  __syncthreads();
  float s = 0.f;
#pragma unroll
  for (int t2 = 0; t2 < 32; ++t2) s += smem[(wid * 32 + t2) * 65 + lane];
  const int r = lane >> 4, bb = lane & 15;
  raw[(size_t)bb * EQKV + e0 + r] = s;
}

// ---------------- Kernel 2: RoPE + scatter new row into caches ------------
__device__ __forceinline__ float rope_val(const float* src, int d, float pos) {
  int i = d & 63;
  float inv_freq = powf(10000.f, -(float)(2 * i) * (1.f / 128.f));
  float ang = pos * inv_freq;
  float s, c;
  sincosf(ang, &s, &c);
  float x = src[d];
  float rot = (d < 64) ? -src[d + 64] : src[d - 64];
  return x * c + rot * s;
}

__global__ void rope_scatter(const float* __restrict__ raw,
                             const void* __restrict__ pos_ids,
                             float* __restrict__ qout,
                             float* __restrict__ kc, float* __restrict__ vc) {
  const int b = blockIdx.y, j = blockIdx.x, d = threadIdx.x;  // 128 threads
  const int* pi = (const int*)pos_ids;
  long long pos = (pi[1] == 0 && pi[0] != 0) ? ((const long long*)pos_ids)[b]
                                             : (long long)pi[b];
  const float fpos = (float)pos;
  if (j < 32) {
    const float* src = raw + (size_t)b * EQKV + j * HD;
    qout[(size_t)b * (NH * HD) + j * HD + d] = rope_val(src, d, fpos);
  } else if (j < 40) {
    int kvh = j - 32;
    const float* src = raw + (size_t)b * EQKV + 4096 + kvh * HD;
    kc[(((size_t)b * NKV + kvh) * SEQ + PASTN) * HD + d] = rope_val(src, d, fpos);
  } else {
    int kvh = j - 40;
    vc[(((size_t)b * NKV + kvh) * SEQ + PASTN) * HD + d] =
        raw[(size_t)b * EQKV + 5120 + kvh * HD + d];
  }
}

// ---------------- Kernel 3: barrier-free fused copy + flash-decode --------
// grid (chunk=8, kv=8, b=16); 4 waves/block. Wave w owns rows
// [chunk*512 + w*128, +128) for ALL 4 heads of its kv group.
// lane = h*16 + g: head h, dims [g*8, g*8+8). No LDS in main loop.
__global__ __launch_bounds__(256, 4) void attn_decode(
    const float* __restrict__ pastK, const float* __restrict__ pastV,
    const float* __restrict__ qv, const float* __restrict__ mask,
    float* __restrict__ kc, float* __restrict__ vc,
    float* __restrict__ part /* [B][32][8][PSTRIDE] */) {
  __shared__ __align__(16) float sm[4][4][132];  // [wave][head][m,l,pad,ctx128]

  const int chunk = blockIdx.x, kv = blockIdx.y, b = blockIdx.z;
  const int tid = threadIdx.x, wid = tid >> 6, lane = tid & 63;
  const int h = lane >> 4, g = lane & 15;

  const float* qp = qv + (size_t)b * (NH * HD) + (kv * 4 + h) * HD + g * 8;
  const v4f q0 = *(const v4f*)qp;
  const v4f q1 = *(const v4f*)(qp + 4);

  const size_t prow = ((size_t)b * NKV + kv) * PASTN;
  const size_t crow = ((size_t)b * NKV + kv) * SEQ;
  const int base = chunk * CHUNKS + wid * 128;
  const float* mrow = mask + (size_t)b * SEQ;

  float m = -1e30f, l = 0.f;
  v4f c0 = {0.f, 0.f, 0.f, 0.f}, c1 = {0.f, 0.f, 0.f, 0.f};

  for (int t = 0; t < 32; ++t) {  // 4 rows per group
    const int s0 = base + t * 4;
    v4f k0r[4], k1r[4], v0r[4], v1r[4];
#pragma unroll
    for (int r = 0; r < 4; ++r) {
      const int s = s0 + r;
      const float *kp, *vp;
      if (s < PASTN) {
        kp = pastK + (prow + s) * HD;
        vp = pastV + (prow + s) * HD;
      } else {
        kp = kc + (crow + s) * HD;
        vp = vc + (crow + s) * HD;
      }
      k0r[r] = __builtin_nontemporal_load((const v4f*)(kp + g * 8));
      k1r[r] = __builtin_nontemporal_load((const v4f*)(kp + g * 8 + 4));
      v0r[r] = __builtin_nontemporal_load((const v4f*)(vp + g * 8));
      v1r[r] = __builtin_nontemporal_load((const v4f*)(vp + g * 8 + 4));
    }
    // write-through cache copy (h==0 lanes cover the full row)
#pragma unroll
    for (int r = 0; r < 4; ++r) {
      const int s = s0 + r;
      if (s < PASTN && h == 0) {
        float* kd = kc + (crow + s) * HD + g * 8;
        float* vd = vc + (crow + s) * HD + g * 8;
        __builtin_nontemporal_store(k0r[r], (v4f*)kd);
        __builtin_nontemporal_store(k1r[r], (v4f*)(kd + 4));
        __builtin_nontemporal_store(v0r[r], (v4f*)vd);
        __builtin_nontemporal_store(v1r[r], (v4f*)(vd + 4));
      }
    }
    // scores (reduced within each 16-lane head group)
    float sc[4];
#pragma unroll
    for (int r = 0; r < 4; ++r) {
      v4f tv = q0 * k0r[r] + q1 * k1r[r];
      float d = tv[0] + tv[1] + tv[2] + tv[3];
      d += __shfl_xor(d, 1);
      d += __shfl_xor(d, 2);
      d += __shfl_xor(d, 4);
      d += __shfl_xor(d, 8);
      sc[r] = d * SCALE + mrow[s0 + r];
    }
    // online softmax (per-lane; identical within head group)
    float gm = fmaxf(fmaxf(sc[0], sc[1]), fmaxf(sc[2], sc[3]));
    float mn = fmaxf(m, gm);
    float alpha = __expf(m - mn);
    l *= alpha;
    c0 *= alpha;
    c1 *= alpha;
    m = mn;
#pragma unroll
    for (int r = 0; r < 4; ++r) {
      float p = __expf(sc[r] - mn);
      l += p;
      c0 += p * v0r[r];
      c1 += p * v1r[r];
    }
  }

  // in-block merge of the 4 wave-slices (one barrier, end of kernel)
  if (g == 0) { sm[wid][h][0] = m; sm[wid][h][1] = l; }
  *(v4f*)(&sm[wid][h][4 + g * 8]) = c0;
  *(v4f*)(&sm[wid][h][8 + g * 8]) = c1;
  __syncthreads();

  // wave `wid` merges head `wid`
  float mstar = -1e30f;
#pragma unroll
  for (int sl = 0; sl < 4; ++sl) mstar = fmaxf(mstar, sm[sl][wid][0]);
  float den = 0.f;
  const int d2 = lane * 2;
  float nx = 0.f, ny = 0.f;
#pragma unroll
  for (int sl = 0; sl < 4; ++sl) {
    float w = __expf(sm[sl][wid][0] - mstar);
    den += w * sm[sl][wid][1];
    nx += w * sm[sl][wid][4 + d2];
    ny += w * sm[sl][wid][4 + d2 + 1];
  }
  float* pp = part + (((size_t)b * NH + kv * 4 + wid) * NCHUNK + chunk) * PSTRIDE;
  if (lane == 0) { pp[0] = mstar; pp[1] = den; }
  float2 nv = {nx, ny};
  *(float2*)(pp + 4 + d2) = nv;
}

// ---------------- Kernel 4: combine chunk partials ------------------------
__global__ void combine(const float* __restrict__ part, float* __restrict__ ctx) {
  const int bh = blockIdx.x;        // 0..511
  const int lane = threadIdx.x;     // 64
  const float* pp = part + (size_t)bh * NCHUNK * PSTRIDE;
  float mstar = -1e30f;
#pragma unroll
  for (int c = 0; c < NCHUNK; ++c) mstar = fmaxf(mstar, pp[c * PSTRIDE]);
  float den = 0.f, nx = 0.f, ny = 0.f;
  const int d2 = lane * 2;
#pragma unroll
  for (int c = 0; c < NCHUNK; ++c) {
    float w = __expf(pp[c * PSTRIDE] - mstar);
    den += w * pp[c * PSTRIDE + 1];
    float2 pv = *(const float2*)(pp + c * PSTRIDE + 4 + d2);
    nx += w * pv.x;
    ny += w * pv.y;
  }
  float inv = 1.0f / den;
  ctx[(size_t)bh * HD + d2] = nx * inv;
  ctx[(size_t)bh * HD + d2 + 1] = ny * inv;
}

// ---------------- Kernel 5: output projection (M=16, N=4096, K=4096) ------
__global__ __launch_bounds__(256) void out_proj(
    const float* __restrict__ ctx, const float* __restrict__ Wo,
    float* __restrict__ out) {
  __shared__ __align__(16) float smem[4 * 32 * 65];
  const int tid = threadIdx.x, wid = tid >> 6, lane = tid & 63;
  const int e0 = blockIdx.x * 16 + wid * 4;

  float acc[4][16];
#pragma unroll
  for (int r = 0; r < 4; ++r)
#pragma unroll
    for (int b = 0; b < 16; ++b) acc[r][b] = 0.f;

  float* ld = smem;  // [16][256]
  for (int k0 = 0; k0 < DMODEL; k0 += 256) {
    __syncthreads();
#pragma unroll
    for (int i = 0; i < 4; ++i) {
      int flat = i * 1024 + tid * 4;
      int b = flat >> 8, c = flat & 255;
      *(v4f*)(&ld[b * 256 + c]) = *(const v4f*)(ctx + (size_t)b * DMODEL + k0 + c);
    }
    __syncthreads();
    v4f w4[4];
#pragma unroll
    for (int r = 0; r < 4; ++r)
      w4[r] = *(const v4f*)(Wo + (size_t)(e0 + r) * DMODEL + k0 + lane * 4);
#pragma unroll
    for (int b = 0; b < 16; ++b) {
      v4f h4 = *(const v4f*)(&ld[b * 256 + lane * 4]);
#pragma unroll
      for (int r = 0; r < 4; ++r) {
        v4f t = w4[r] * h4;
        acc[r][b] += t[0] + t[1] + t[2] + t[3];
      }
    }
  }

#pragma unroll
  for (int r = 0; r < 4; ++r)
#pragma unroll
    for (int b = 0; b < 16; ++b) acc[r][b] += __shfl_xor(acc[r][b], 32);

  __syncthreads();
  if (lane < 32) {
#pragma unroll
    for (int r = 0; r < 4; ++r)
#pragma unroll
      for (int b = 0; b < 16; ++b)
        smem[(wid * 32 + lane) * 65 + r * 16 + b] = acc[r][b];
  }
  __syncthreads();
  float s = 0.f;
#pragma unroll
  for (int t2 = 0; t2 < 32; ++t2) s += smem[(wid * 32 + t2) * 65 + lane];
  const int r = lane >> 4, bb = lane & 15;
  out[(size_t)bb * DMODEL + e0 + r] = s;
}

// ---------------------------------------------------------------------------
extern "C" void kernel_launch(void* const* d_in, const int* in_sizes, int n_in,
                              void* d_out, int out_size, void* d_ws, size_t ws_size,
                              hipStream_t stream) {
  const float* hs    = (const float*)d_in[0];
  const float* mask  = (const float*)d_in[1];
  const void*  pos   = d_in[2];
  const float* pastK = (const float*)d_in[3];
  const float* pastV = (const float*)d_in[4];
  const float* Wq    = (const float*)d_in[5];
  const float* Wk    = (const float*)d_in[6];
  const float* Wv    = (const float*)d_in[7];
  const float* Wo    = (const float*)d_in[8];

  float* out  = (float*)d_out;
  float* attn = out;                                        // 16*4096
  float* kc   = out + (size_t)NB * DMODEL;                  // 16*8*4096*128
  float* vc   = kc + (size_t)NB * NKV * SEQ * HD;

  float* ws      = (float*)d_ws;
  float* ws_q    = ws;                                      // 65536
  float* ws_raw  = ws_q + (size_t)NB * NH * HD;             // 98304
  float* ws_part = ws_raw + (size_t)NB * EQKV;              // 16*32*8*136
  float* ws_ctx  = ws_part + (size_t)NB * NH * NCHUNK * PSTRIDE; // 65536

  qkv_proj<<<EQKV / 16, 256, 0, stream>>>(hs, Wq, Wk, Wv, ws_raw);
  rope_scatter<<<dim3(48, NB), 128, 0, stream>>>(ws_raw, pos, ws_q, kc, vc);
  attn_decode<<<dim3(NCHUNK, NKV, NB), 256, 0, stream>>>(pastK, pastV, ws_q, mask,
                                                         kc, vc, ws_part);
  combine<<<NB * NH, 64, 0, stream>>>(ws_part, ws_ctx);
  out_proj<<<DMODEL / 16, 256, 0, stream>>>(ws_ctx, Wo, attn);
}